// Round 5
// baseline (510.317 us; speedup 1.0000x reference)
//
#include <hip/hip_runtime.h>
#include <hip/hip_bf16.h>
#include <hip/hip_cooperative_groups.h>

namespace cg = cooperative_groups;

#define T_DIM 64
#define B_DIM 4
#define INP_D 768
#define Q_D   384
#define E_D   384
#define DFF_D 1536
#define NTOK  256
#define GRID_BLOCKS 256

__device__ __forceinline__ float sigf(float x)  { return 1.0f / (1.0f + __expf(-x)); }
__device__ __forceinline__ float elu1f(float x) { return x > 0.0f ? x + 1.0f : __expf(x); }

// Workspace float offsets (all disjoint; ~22.4 MB total)
#define WS_PF_FG    0           // [2][256][384]
#define WS_PF_PARTS 196608      // [2][256][1536]
#define WS_PATT     983040      // [8][256][384]
#define WS_ATTN     1769472     // [256][384]
#define WS_PF_PROJ  1867776     // [4][256][768]
#define WS_H        2654208     // [256][768]
#define WS_PF1      2850816     // [2][256][1536]
#define WS_PF2      3637248     // [2][256][1536]
#define WS_G        4423680     // [256][1536]
#define WS_PF_O     4816896     // [4][256][768]

// ---------------------------------------------------------------------------
// f32 GEMM tile job: 64x64 C-tile, 256 threads, acc 4x4/thread, k-slab [k0,k0+KSUB)
// A[256 x K] row-major, B[K x N] row-major, P = partial slab (same layout as C).
// LDS: As/Bs are k-major [16][68].
// ---------------------------------------------------------------------------
template<int K, int N, int KSUB>
__device__ __forceinline__ void gemm_job(const float* __restrict__ A,
                                         const float* __restrict__ Bm,
                                         float* __restrict__ P,
                                         int m0, int n0, int k0,
                                         float* __restrict__ As,
                                         float* __restrict__ Bs) {
  const int tid = threadIdx.x;
  const int tx = tid & 15, ty = tid >> 4;
  const int ar = tid >> 2, ac = (tid & 3) << 2;
  const int br = tid >> 4, bc = (tid & 15) << 2;
  float acc[4][4] = {};
  float4 ra = *(const float4*)&A[(size_t)(m0 + ar) * K + k0 + ac];
  float4 rb = *(const float4*)&Bm[(size_t)(k0 + br) * N + n0 + bc];
  for (int kb = 0; kb < KSUB; kb += 16) {
    if (kb) __syncthreads();
    As[(ac + 0) * 68 + ar] = ra.x;
    As[(ac + 1) * 68 + ar] = ra.y;
    As[(ac + 2) * 68 + ar] = ra.z;
    As[(ac + 3) * 68 + ar] = ra.w;
    *(float4*)&Bs[br * 68 + bc] = rb;
    __syncthreads();
    if (kb + 16 < KSUB) {
      ra = *(const float4*)&A[(size_t)(m0 + ar) * K + k0 + kb + 16 + ac];
      rb = *(const float4*)&Bm[(size_t)(k0 + kb + 16 + br) * N + n0 + bc];
    }
#pragma unroll
    for (int kk = 0; kk < 16; ++kk) {
      const float4 a4 = *(const float4*)&As[kk * 68 + (ty << 2)];
      const float4 b4 = *(const float4*)&Bs[kk * 68 + (tx << 2)];
      const float a[4] = {a4.x, a4.y, a4.z, a4.w};
      const float b[4] = {b4.x, b4.y, b4.z, b4.w};
#pragma unroll
      for (int i = 0; i < 4; ++i)
#pragma unroll
        for (int j = 0; j < 4; ++j) acc[i][j] = fmaf(a[i], b[j], acc[i][j]);
    }
  }
  __syncthreads();
#pragma unroll
  for (int i = 0; i < 4; ++i)
    *(float4*)&P[(size_t)(m0 + (ty << 2) + i) * N + n0 + (tx << 2)] =
        make_float4(acc[i][0], acc[i][1], acc[i][2], acc[i][3]);
}

// Dual-B variant (FFN W1/W2 share the A tile)
template<int K, int N, int KSUB>
__device__ __forceinline__ void gemm_dual_job(const float* __restrict__ A,
                                              const float* __restrict__ B1,
                                              const float* __restrict__ B2,
                                              float* __restrict__ P1,
                                              float* __restrict__ P2,
                                              int m0, int n0, int k0,
                                              float* __restrict__ As,
                                              float* __restrict__ B1s,
                                              float* __restrict__ B2s) {
  const int tid = threadIdx.x;
  const int tx = tid & 15, ty = tid >> 4;
  const int ar = tid >> 2, ac = (tid & 3) << 2;
  const int br = tid >> 4, bc = (tid & 15) << 2;
  float acc1[4][4] = {}, acc2[4][4] = {};
  float4 ra  = *(const float4*)&A[(size_t)(m0 + ar) * K + k0 + ac];
  float4 rb1 = *(const float4*)&B1[(size_t)(k0 + br) * N + n0 + bc];
  float4 rb2 = *(const float4*)&B2[(size_t)(k0 + br) * N + n0 + bc];
  for (int kb = 0; kb < KSUB; kb += 16) {
    if (kb) __syncthreads();
    As[(ac + 0) * 68 + ar] = ra.x;
    As[(ac + 1) * 68 + ar] = ra.y;
    As[(ac + 2) * 68 + ar] = ra.z;
    As[(ac + 3) * 68 + ar] = ra.w;
    *(float4*)&B1s[br * 68 + bc] = rb1;
    *(float4*)&B2s[br * 68 + bc] = rb2;
    __syncthreads();
    if (kb + 16 < KSUB) {
      ra  = *(const float4*)&A[(size_t)(m0 + ar) * K + k0 + kb + 16 + ac];
      rb1 = *(const float4*)&B1[(size_t)(k0 + kb + 16 + br) * N + n0 + bc];
      rb2 = *(const float4*)&B2[(size_t)(k0 + kb + 16 + br) * N + n0 + bc];
    }
#pragma unroll
    for (int kk = 0; kk < 16; ++kk) {
      const float4 a4 = *(const float4*)&As[kk * 68 + (ty << 2)];
      const float4 c1 = *(const float4*)&B1s[kk * 68 + (tx << 2)];
      const float4 c2 = *(const float4*)&B2s[kk * 68 + (tx << 2)];
      const float a[4]  = {a4.x, a4.y, a4.z, a4.w};
      const float b1[4] = {c1.x, c1.y, c1.z, c1.w};
      const float b2[4] = {c2.x, c2.y, c2.z, c2.w};
#pragma unroll
      for (int i = 0; i < 4; ++i)
#pragma unroll
        for (int j = 0; j < 4; ++j) {
          acc1[i][j] = fmaf(a[i], b1[j], acc1[i][j]);
          acc2[i][j] = fmaf(a[i], b2[j], acc2[i][j]);
        }
    }
  }
  __syncthreads();
#pragma unroll
  for (int i = 0; i < 4; ++i) {
    size_t o = (size_t)(m0 + (ty << 2) + i) * N + n0 + (tx << 2);
    *(float4*)&P1[o] = make_float4(acc1[i][0], acc1[i][1], acc1[i][2], acc1[i][3]);
    *(float4*)&P2[o] = make_float4(acc2[i][0], acc2[i][1], acc2[i][2], acc2[i][3]);
  }
}

// Forget GEMM job: A synthesized on the fly (mixed = mu*inp + (1-mu)*last)
__device__ __forceinline__ void gemm_forget_job(const float* __restrict__ inp,
                                                const float* __restrict__ is_first,
                                                const float* __restrict__ init_inp,
                                                const float* __restrict__ mu,
                                                const float* __restrict__ Bm,
                                                float* __restrict__ P,
                                                int m0, int n0, int k0,
                                                float* __restrict__ As,
                                                float* __restrict__ Bs) {
  constexpr int K = INP_D, N = Q_D, KSUB = 384;
  const int tid = threadIdx.x;
  const int tx = tid & 15, ty = tid >> 4;
  const int ar = tid >> 2, ac = (tid & 3) << 2;
  const int br = tid >> 4, bc = (tid & 15) << 2;
  const int m = m0 + ar, t = m >> 2, b = m & 3;
  const float fr = (t == 0) ? 1.0f : is_first[m];
  float acc[4][4] = {};
  auto synthA = [&](int kc) {
    float4 xi = *(const float4*)&inp[(size_t)m * K + kc];
    float4 la = (fr > 0.5f) ? *(const float4*)&init_inp[b * K + kc]
                            : *(const float4*)&inp[(size_t)(m - 4) * K + kc];
    float4 m4 = *(const float4*)&mu[kc];
    float4 r;
    r.x = m4.x * xi.x + (1.0f - m4.x) * la.x;
    r.y = m4.y * xi.y + (1.0f - m4.y) * la.y;
    r.z = m4.z * xi.z + (1.0f - m4.z) * la.z;
    r.w = m4.w * xi.w + (1.0f - m4.w) * la.w;
    return r;
  };
  float4 ra = synthA(k0 + ac);
  float4 rb = *(const float4*)&Bm[(size_t)(k0 + br) * N + n0 + bc];
  for (int kb = 0; kb < KSUB; kb += 16) {
    if (kb) __syncthreads();
    As[(ac + 0) * 68 + ar] = ra.x;
    As[(ac + 1) * 68 + ar] = ra.y;
    As[(ac + 2) * 68 + ar] = ra.z;
    As[(ac + 3) * 68 + ar] = ra.w;
    *(float4*)&Bs[br * 68 + bc] = rb;
    __syncthreads();
    if (kb + 16 < KSUB) {
      ra = synthA(k0 + kb + 16 + ac);
      rb = *(const float4*)&Bm[(size_t)(k0 + kb + 16 + br) * N + n0 + bc];
    }
#pragma unroll
    for (int kk = 0; kk < 16; ++kk) {
      const float4 a4 = *(const float4*)&As[kk * 68 + (ty << 2)];
      const float4 b4 = *(const float4*)&Bs[kk * 68 + (tx << 2)];
      const float a[4] = {a4.x, a4.y, a4.z, a4.w};
      const float b[4] = {b4.x, b4.y, b4.z, b4.w};
#pragma unroll
      for (int i = 0; i < 4; ++i)
#pragma unroll
        for (int j = 0; j < 4; ++j) acc[i][j] = fmaf(a[i], b[j], acc[i][j]);
    }
  }
  __syncthreads();
#pragma unroll
  for (int i = 0; i < 4; ++i)
    *(float4*)&P[(size_t)(m0 + (ty << 2) + i) * N + n0 + (tx << 2)] =
        make_float4(acc[i][0], acc[i][1], acc[i][2], acc[i][3]);
}

// ---------------------------------------------------------------------------
// Scan job: segmented recurrence + query contraction, epilogues (sigmoid/elu/
// drops on the GEMM partial slabs) fused into the staging reads.
// job = ((qc*4 + b)*6 + eb); q-chunk 48, 12 states/thread, 4 q-subgroups.
// ---------------------------------------------------------------------------
__device__ void scan_job(int j, const float* __restrict__ pf_fg,
                         const float* __restrict__ pf_parts,
                         const float* __restrict__ drops,
                         const float* __restrict__ is_first,
                         const float* __restrict__ init_state,
                         float* __restrict__ patt,
                         float* __restrict__ stg, float* __restrict__ pacc) {
  const int tid = threadIdx.x;
  const int eb = j % 6, r2 = j / 6;
  const int qc = r2 >> 2, b = r2 & 3;
  const int e  = eb * 64 + (tid & 63);
  const int qg = tid >> 6;
  const int q0 = qc * 48 + qg * 12;

  float s[12], ini[12];
#pragma unroll
  for (int jj = 0; jj < 12; ++jj) {
    ini[jj] = init_state[((size_t)b * Q_D + q0 + jj) * E_D + e];
    s[jj]   = ini[jj];
  }

  auto stage_val = [&](int tok) -> float {   // valid for tid < 144
    const int which = tid / 48, o = tid % 48;
    const int qcol = qc * 48 + o;
    const float d = drops[tok];
    if (which == 0) {
      float raw = pf_fg[(size_t)tok * Q_D + qcol] + pf_fg[98304 + (size_t)tok * Q_D + qcol];
      return (sigf(raw) - 1.0f) * d + 1.0f;
    }
    const int col = (which == 1) ? Q_D + qcol : qcol;   // keyv : query
    float raw = (pf_parts[(size_t)tok * DFF_D + col] +
                 pf_parts[393216 + (size_t)tok * DFF_D + col]) * d;
    return elu1f(raw);
  };
  auto v_val = [&](int tok) -> float {
    const float d = drops[tok];
    float p2 = (pf_parts[(size_t)tok * DFF_D + 768 + e] +
                pf_parts[393216 + (size_t)tok * DFF_D + 768 + e]) * d;
    float p3 = (pf_parts[(size_t)tok * DFF_D + 1152 + e] +
                pf_parts[393216 + (size_t)tok * DFF_D + 1152 + e]) * d;
    return sigf(p2) * p3;
  };

  float stage_r = 0.0f, v_r, if_r;
  {
    const int tok = b;                        // t = 0
    if (tid < 144) stage_r = stage_val(tok);
    v_r  = v_val(tok);
    if_r = 0.0f;
  }

  for (int t = 0; t < T_DIM; ++t) {
    const int tok = t * B_DIM + b;
    if (tid < 144) stg[tid] = stage_r;
    const float v  = v_r;
    const float ff = if_r;
    __syncthreads();
    if (t + 1 < T_DIM) {
      const int tok1 = tok + B_DIM;
      if (tid < 144) stage_r = stage_val(tok1);
      v_r  = v_val(tok1);
      if_r = is_first[tok1];
    }
    if (ff > 0.5f) {
#pragma unroll
      for (int jj = 0; jj < 12; ++jj) s[jj] = ini[jj];
    }
    const float4* f4 = (const float4*)&stg[qg * 12];
    const float4* k4 = (const float4*)&stg[48 + qg * 12];
    const float4* q4 = (const float4*)&stg[96 + qg * 12];
    float p = 0.0f;
#pragma unroll
    for (int jj = 0; jj < 3; ++jj) {
      const float4 fv = f4[jj], kv = k4[jj], qv = q4[jj];
#pragma unroll
      for (int j2 = 0; j2 < 4; ++j2) {
        const int sj = jj * 4 + j2;
        s[sj] = fmaf((&fv.x)[j2], s[sj], (&kv.x)[j2] * v);
        p     = fmaf((&qv.x)[j2], s[sj], p);
      }
    }
    pacc[tid] = p;
    __syncthreads();
    if (tid < 64) {
      float r = pacc[tid] + pacc[tid + 64] + pacc[tid + 128] + pacc[tid + 192];
      patt[((size_t)qc * NTOK + tok) * E_D + eb * 64 + tid] = r;
    }
    __syncthreads();
  }
}

// ---------------------------------------------------------------------------
// The cooperative mega-kernel: 9 phases separated by grid.sync().
// ---------------------------------------------------------------------------
__global__ __launch_bounds__(256) void mega(const float* __restrict__ inp,
                                            const float* __restrict__ is_first,
                                            const float* __restrict__ drops,
                                            const float* __restrict__ init_inp,
                                            const float* __restrict__ init_state,
                                            const float* __restrict__ mix_mu,
                                            const float* __restrict__ mix_W,
                                            const float* __restrict__ layer_W,
                                            const float* __restrict__ proj_W,
                                            const float* __restrict__ rms_w,
                                            const float* __restrict__ ln_w,
                                            const float* __restrict__ ln_b,
                                            const float* __restrict__ W1,
                                            const float* __restrict__ W2,
                                            const float* __restrict__ W3,
                                            float* __restrict__ out,
                                            float* __restrict__ ws) {
  cg::grid_group grid = cg::this_grid();
  __shared__ float smem[3264];
  float* As  = smem;
  float* Bs  = smem + 1088;
  float* B2s = smem + 2176;
  const int bid = blockIdx.x, tid = threadIdx.x;

  float* pf_fg    = ws + WS_PF_FG;
  float* pf_parts = ws + WS_PF_PARTS;
  float* patt     = ws + WS_PATT;
  float* attn     = ws + WS_ATTN;
  float* pf_proj  = ws + WS_PF_PROJ;
  float* h        = ws + WS_H;
  float* pf1      = ws + WS_PF1;
  float* pf2      = ws + WS_PF2;
  float* g        = ws + WS_G;
  float* pf_o     = ws + WS_PF_O;

  // ---- P1: forget GEMM (48 jobs) + parts GEMM (192 jobs) ----
  for (int j = bid; j < 240; j += GRID_BLOCKS) {
    if (j < 48) {
      int t = j >> 1, s = j & 1;
      gemm_forget_job(inp, is_first, init_inp, mix_mu, mix_W, pf_fg + (size_t)s * 98304,
                      (t / 6) * 64, (t % 6) * 64, s * 384, As, Bs);
    } else {
      int pj = j - 48, t = pj >> 1, s = pj & 1;
      gemm_job<INP_D, DFF_D, 384>(inp, layer_W, pf_parts + (size_t)s * 393216,
                                  (t / 24) * 64, (t % 24) * 64, s * 384, As, Bs);
    }
  }
  grid.sync();

  // ---- P2: segmented scan (192 jobs), epilogues fused into staging ----
  for (int j = bid; j < 192; j += GRID_BLOCKS)
    scan_job(j, pf_fg, pf_parts, drops, is_first, init_state, patt, smem, smem + 160);
  grid.sync();

  // ---- P3: sum 8 scan slabs + RMS norm -> attn (256 jobs) ----
  for (int tok = bid; tok < NTOK; tok += GRID_BLOCKS) {
    float a0 = 0.0f, a1 = 0.0f;
#pragma unroll
    for (int qc = 0; qc < 8; ++qc) a0 += patt[(size_t)qc * 98304 + (size_t)tok * E_D + tid];
    if (tid < 128) {
#pragma unroll
      for (int qc = 0; qc < 8; ++qc) a1 += patt[(size_t)qc * 98304 + (size_t)tok * E_D + 256 + tid];
    }
    float ss = a0 * a0 + a1 * a1;
#pragma unroll
    for (int off = 32; off; off >>= 1) ss += __shfl_down(ss, off, 64);
    if ((tid & 63) == 0) smem[tid >> 6] = ss;
    __syncthreads();
    float tot = smem[0] + smem[1] + smem[2] + smem[3];
    const float sc = rsqrtf(tot * (1.0f / E_D) + 1e-6f);
    attn[(size_t)tok * E_D + tid] = a0 * sc * rms_w[tid];
    if (tid < 128) attn[(size_t)tok * E_D + 256 + tid] = a1 * sc * rms_w[256 + tid];
    __syncthreads();
  }
  grid.sync();

  // ---- P4: proj GEMM (48 tiles x S=4 = 192 jobs) ----
  for (int j = bid; j < 192; j += GRID_BLOCKS) {
    int t = j >> 2, s = j & 3;
    gemm_job<E_D, INP_D, 96>(attn, proj_W, pf_proj + (size_t)s * 196608,
                             (t / 12) * 64, (t % 12) * 64, s * 96, As, Bs);
  }
  grid.sync();

  // ---- P5: sum 4 proj slabs + residual + LayerNorm -> h (256 jobs) ----
  for (int tok = bid; tok < NTOK; tok += GRID_BLOCKS) {
    float x[3], s1 = 0.0f, s2 = 0.0f;
#pragma unroll
    for (int i = 0; i < 3; ++i) {
      int c = i * 256 + tid;
      float a = inp[(size_t)tok * INP_D + c];
#pragma unroll
      for (int s = 0; s < 4; ++s) a += pf_proj[(size_t)s * 196608 + (size_t)tok * INP_D + c];
      x[i] = a;
      s1 += a;
      s2 = fmaf(a, a, s2);
    }
#pragma unroll
    for (int off = 32; off; off >>= 1) {
      s1 += __shfl_down(s1, off, 64);
      s2 += __shfl_down(s2, off, 64);
    }
    if ((tid & 63) == 0) { smem[tid >> 6] = s1; smem[8 + (tid >> 6)] = s2; }
    __syncthreads();
    s1 = smem[0] + smem[1] + smem[2] + smem[3];
    s2 = smem[8] + smem[9] + smem[10] + smem[11];
    const float mean = s1 * (1.0f / INP_D);
    const float var  = s2 * (1.0f / INP_D) - mean * mean;
    const float sc   = rsqrtf(var + 1e-5f);
#pragma unroll
    for (int i = 0; i < 3; ++i) {
      int c = i * 256 + tid;
      h[(size_t)tok * INP_D + c] = (x[i] - mean) * sc * ln_w[c] + ln_b[c];
    }
    __syncthreads();
  }
  grid.sync();

  // ---- P6: FFN dual GEMM (96 tiles x S=2 = 192 jobs) ----
  for (int j = bid; j < 192; j += GRID_BLOCKS) {
    int t = j >> 1, s = j & 1;
    gemm_dual_job<INP_D, DFF_D, 384>(h, W1, W2, pf1 + (size_t)s * 393216,
                                     pf2 + (size_t)s * 393216,
                                     (t / 24) * 64, (t % 24) * 64, s * 384, As, Bs, B2s);
  }
  grid.sync();

  // ---- P7: g = silu(f1) * f2 (elementwise) ----
#pragma unroll
  for (int i = 0; i < 6; ++i) {
    int idx = i * 65536 + bid * 256 + tid;
    float a = pf1[idx] + pf1[393216 + idx];
    float b = pf2[idx] + pf2[393216 + idx];
    g[idx] = a * sigf(a) * b;
  }
  grid.sync();

  // ---- P8: out GEMM (48 tiles x S=4 = 192 jobs) ----
  for (int j = bid; j < 192; j += GRID_BLOCKS) {
    int t = j >> 2, s = j & 3;
    gemm_job<DFF_D, INP_D, 384>(g, W3, pf_o + (size_t)s * 196608,
                                (t / 12) * 64, (t % 12) * 64, s * 384, As, Bs);
  }
  grid.sync();

  // ---- P9: sum 4 out slabs -> out ----
#pragma unroll
  for (int i = 0; i < 3; ++i) {
    int idx = i * 65536 + bid * 256 + tid;
    out[idx] = pf_o[idx] + pf_o[196608 + idx] + pf_o[393216 + idx] + pf_o[589824 + idx];
  }
}

extern "C" void kernel_launch(void* const* d_in, const int* in_sizes, int n_in,
                              void* d_out, int out_size, void* d_ws, size_t ws_size,
                              hipStream_t stream) {
  (void)in_sizes; (void)n_in; (void)out_size; (void)ws_size;
  const float* inp        = (const float*)d_in[0];
  const float* is_first   = (const float*)d_in[1];
  const float* drops      = (const float*)d_in[2];
  const float* init_inp   = (const float*)d_in[3];
  const float* init_state = (const float*)d_in[4];
  const float* mix_mu     = (const float*)d_in[5];
  const float* mix_W      = (const float*)d_in[6];
  const float* layer_W    = (const float*)d_in[7];
  const float* proj_W     = (const float*)d_in[8];
  const float* rms_w      = (const float*)d_in[9];
  const float* ln_w       = (const float*)d_in[10];
  const float* ln_b       = (const float*)d_in[11];
  const float* W1         = (const float*)d_in[12];
  const float* W2         = (const float*)d_in[13];
  const float* W3         = (const float*)d_in[14];
  float* out = (float*)d_out;
  float* ws  = (float*)d_ws;

  void* args[] = {
      (void*)&inp, (void*)&is_first, (void*)&drops, (void*)&init_inp,
      (void*)&init_state, (void*)&mix_mu, (void*)&mix_W, (void*)&layer_W,
      (void*)&proj_W, (void*)&rms_w, (void*)&ln_w, (void*)&ln_b,
      (void*)&W1, (void*)&W2, (void*)&W3, (void*)&out, (void*)&ws};
  hipLaunchCooperativeKernel((const void*)mega, dim3(GRID_BLOCKS), dim3(256),
                             args, 0, stream);
}

// Round 8
// 209.917 us; speedup vs baseline: 2.4310x; 2.4310x over previous
//
#include <hip/hip_runtime.h>
#include <hip/hip_bf16.h>

#define T_DIM 64
#define B_DIM 4
#define INP_D 768
#define Q_D   384
#define E_D   384
#define DFF_D 1536
#define NTOK  256

typedef short bf16x8 __attribute__((ext_vector_type(8)));
typedef float f32x4  __attribute__((ext_vector_type(4)));

__device__ __forceinline__ float sigf(float x)  { return 1.0f / (1.0f + __expf(-x)); }
__device__ __forceinline__ float elu1f(float x) { return x > 0.0f ? x + 1.0f : __expf(x); }

__device__ __forceinline__ short f2b(float x) {
  union { __hip_bfloat16 b; short s; } u;
  u.b = __float2bfloat16(x);
  return u.s;
}
__device__ __forceinline__ bf16x8 cvt8(float4 a, float4 b) {
  bf16x8 r;
  r[0] = f2b(a.x); r[1] = f2b(a.y); r[2] = f2b(a.z); r[3] = f2b(a.w);
  r[4] = f2b(b.x); r[5] = f2b(b.y); r[6] = f2b(b.z); r[7] = f2b(b.w);
  return r;
}

// ---------------------------------------------------------------------------
// Workspace layout. f32 region then packed-bf16 weight region.
// ---------------------------------------------------------------------------
#define WS_FORGET 0
#define WS_QUERY  98304
#define WS_KEYV   196608
#define WS_VALUE  294912
#define WS_PATT   393216      // [8][256][384]
#define WS_ATTN   1179648
#define WS_HPRE   1277952
#define WS_H      1474560
#define WS_G      1671168     // [256][1536]
#define WS_BF     2064384     // bf16 region start (float offset; 16B aligned)
// bf16-element offsets inside the packed region:
#define PK_MIX   0            // 768x384
#define PK_LAYER 294912       // 768x1536
#define PK_PROJ  1474560      // 384x768
#define PK_W1    1769472      // 768x1536
#define PK_W2    2949120      // 768x1536
#define PK_W3    4128768      // 1536x768  (end 5308416)

// ---------------------------------------------------------------------------
// Weight conversion: f32 [K][N] row-major -> packed bf16 MFMA-B fragments.
// Packed block (kb, bn) covers k in [kb*32, +32), n in [bn*16, +16):
//   elem(lane, j) = B[kb*32 + (lane>>4)*8 + j][bn*16 + (lane&15)]
//   stored at block_base + lane*8 + j  (block_base = (kb*(N/16)+bn)*512)
// One 256-thread block converts a 32k x 64n region (4 packed blocks) via LDS.
// ---------------------------------------------------------------------------
__global__ __launch_bounds__(256) void k_conv(const float* __restrict__ mixW,
                                              const float* __restrict__ layerW,
                                              const float* __restrict__ projW,
                                              const float* __restrict__ W1,
                                              const float* __restrict__ W2,
                                              const float* __restrict__ W3,
                                              short* __restrict__ wsb) {
  const int blk = blockIdx.x;
  const float* src; short* dst; int N, kb, nb64;
  if (blk < 144)        { src = mixW;   dst = wsb + PK_MIX;   N = 384;  int r = blk;        kb = r / 6;  nb64 = r % 6; }
  else if (blk < 720)   { src = layerW; dst = wsb + PK_LAYER; N = 1536; int r = blk - 144;  kb = r / 24; nb64 = r % 24; }
  else if (blk < 864)   { src = projW;  dst = wsb + PK_PROJ;  N = 768;  int r = blk - 720;  kb = r / 12; nb64 = r % 12; }
  else if (blk < 1440)  { src = W1;     dst = wsb + PK_W1;    N = 1536; int r = blk - 864;  kb = r / 24; nb64 = r % 24; }
  else if (blk < 2016)  { src = W2;     dst = wsb + PK_W2;    N = 1536; int r = blk - 1440; kb = r / 24; nb64 = r % 24; }
  else                  { src = W3;     dst = wsb + PK_W3;    N = 768;  int r = blk - 2016; kb = r / 12; nb64 = r % 12; }

  __shared__ float lds[32][68];
  const int tid = threadIdx.x;
  { // coalesced read 32 x 64 f32
    const int r = tid >> 3, c8 = (tid & 7) * 8;
    const float* p = &src[(size_t)(kb * 32 + r) * N + nb64 * 64 + c8];
    *(float4*)&lds[r][c8]     = *(const float4*)p;
    *(float4*)&lds[r][c8 + 4] = *(const float4*)(p + 4);
  }
  __syncthreads();
  { // packed write: 4 blocks x 64 lanes x 16B
    const int nb = tid >> 6, lane = tid & 63, g = lane >> 4, c = lane & 15;
    unsigned int w[4];
#pragma unroll
    for (int jj = 0; jj < 4; ++jj) {
      unsigned short lo = (unsigned short)f2b(lds[g * 8 + jj * 2][nb * 16 + c]);
      unsigned short hi = (unsigned short)f2b(lds[g * 8 + jj * 2 + 1][nb * 16 + c]);
      w[jj] = (unsigned int)lo | ((unsigned int)hi << 16);
    }
    const int N16 = N >> 4;
    size_t o = ((size_t)kb * N16 + (nb64 * 4 + nb)) * 512 + lane * 8;
    uint4 pk; pk.x = w[0]; pk.y = w[1]; pk.z = w[2]; pk.w = w[3];
    *(uint4*)&dst[o] = pk;
  }
}

// ---------------------------------------------------------------------------
// MFMA core: one wave computes 16 rows x 64 cols (4 subtiles) per B matrix.
// No LDS: A converted in-register, B frags loaded as dwordx4 from packed.
// 1-deep register prefetch; f32 accumulate via mfma_f32_16x16x32_bf16.
// ---------------------------------------------------------------------------
template<int KSTEPS, bool DUAL, class ALoad>
__device__ __forceinline__ void mm_core(ALoad loadA,
                                        const short* __restrict__ B1, int bn1, int N16a,
                                        const short* __restrict__ B2, int bn2, int N16b,
                                        int lane, f32x4* acc1, f32x4* acc2) {
  bf16x8 a_c = loadA(0);
  bf16x8 b1c[4], b2c[4];
#pragma unroll
  for (int s = 0; s < 4; ++s)
    b1c[s] = *(const bf16x8*)&B1[((size_t)(bn1 + s)) * 512 + lane * 8];
  if constexpr (DUAL) {
#pragma unroll
    for (int s = 0; s < 4; ++s)
      b2c[s] = *(const bf16x8*)&B2[((size_t)(bn2 + s)) * 512 + lane * 8];
  }
#pragma unroll 2
  for (int kb = 0; kb < KSTEPS; ++kb) {
    bf16x8 a_n = a_c;
    bf16x8 b1n[4], b2n[4];
    if (kb + 1 < KSTEPS) {
      a_n = loadA(kb + 1);
#pragma unroll
      for (int s = 0; s < 4; ++s)
        b1n[s] = *(const bf16x8*)&B1[((size_t)(kb + 1) * N16a + bn1 + s) * 512 + lane * 8];
      if constexpr (DUAL) {
#pragma unroll
        for (int s = 0; s < 4; ++s)
          b2n[s] = *(const bf16x8*)&B2[((size_t)(kb + 1) * N16b + bn2 + s) * 512 + lane * 8];
      }
    }
#pragma unroll
    for (int s = 0; s < 4; ++s)
      acc1[s] = __builtin_amdgcn_mfma_f32_16x16x32_bf16(a_c, b1c[s], acc1[s], 0, 0, 0);
    if constexpr (DUAL) {
#pragma unroll
      for (int s = 0; s < 4; ++s)
        acc2[s] = __builtin_amdgcn_mfma_f32_16x16x32_bf16(a_c, b2c[s], acc2[s], 0, 0, 0);
    }
    a_c = a_n;
#pragma unroll
    for (int s = 0; s < 4; ++s) b1c[s] = b1n[s];
    if constexpr (DUAL) {
#pragma unroll
      for (int s = 0; s < 4; ++s) b2c[s] = b2n[s];
    }
  }
}

#define WAVE_SETUP  const int tid = threadIdx.x, w = tid >> 6, l = tid & 63; \
                    const int m0 = blockIdx.x * 64; \
                    const int rowA = m0 + w * 16 + (l & 15); \
                    const int kg = (l >> 4) * 8; (void)kg;

// ---------------------------------------------------------------------------
// forget = (sigmoid(mixed @ mix_W) - 1)*drops + 1, mixed synthesized on the fly
// ---------------------------------------------------------------------------
__global__ __launch_bounds__(256) void k_fg(const float* __restrict__ inp,
                                            const float* __restrict__ is_first,
                                            const float* __restrict__ init_inp,
                                            const float* __restrict__ mu,
                                            const short* __restrict__ Bp,
                                            const float* __restrict__ drops,
                                            float* __restrict__ forget) {
  WAVE_SETUP
  const int n0 = blockIdx.y * 64, bn = blockIdx.y * 4;
  const int tt = rowA >> 2, bb = rowA & 3;
  const float fr = (tt == 0) ? 1.0f : is_first[rowA];
  const float* lastp = (fr > 0.5f) ? &init_inp[bb * INP_D] : &inp[(size_t)(rowA - 4) * INP_D];
  const float* inpp  = &inp[(size_t)rowA * INP_D];
  auto loadA = [&](int kb) -> bf16x8 {
    const int k = kb * 32 + kg;
    float4 x0 = *(const float4*)&inpp[k],  x1 = *(const float4*)&inpp[k + 4];
    float4 l0 = *(const float4*)&lastp[k], l1 = *(const float4*)&lastp[k + 4];
    float4 m0v = *(const float4*)&mu[k],   m1v = *(const float4*)&mu[k + 4];
    float4 r0, r1;
    r0.x = m0v.x * x0.x + (1.0f - m0v.x) * l0.x;
    r0.y = m0v.y * x0.y + (1.0f - m0v.y) * l0.y;
    r0.z = m0v.z * x0.z + (1.0f - m0v.z) * l0.z;
    r0.w = m0v.w * x0.w + (1.0f - m0v.w) * l0.w;
    r1.x = m1v.x * x1.x + (1.0f - m1v.x) * l1.x;
    r1.y = m1v.y * x1.y + (1.0f - m1v.y) * l1.y;
    r1.z = m1v.z * x1.z + (1.0f - m1v.z) * l1.z;
    r1.w = m1v.w * x1.w + (1.0f - m1v.w) * l1.w;
    return cvt8(r0, r1);
  };
  f32x4 acc[4];
#pragma unroll
  for (int s = 0; s < 4; ++s) acc[s] = (f32x4){0.f, 0.f, 0.f, 0.f};
  mm_core<24, false>(loadA, Bp, bn, 24, nullptr, 0, 0, l, acc, nullptr);
#pragma unroll
  for (int i = 0; i < 4; ++i) {
    const int row = m0 + w * 16 + ((l >> 4) << 2) + i;
    const float d = drops[row];
#pragma unroll
    for (int s = 0; s < 4; ++s) {
      const int col = n0 + s * 16 + (l & 15);
      forget[(size_t)row * Q_D + col] = (sigf(acc[s][i]) - 1.0f) * d + 1.0f;
    }
  }
}

// ---------------------------------------------------------------------------
// parts GEMM: jy<6 -> query (elu+1), jy<12 -> keyv (elu+1),
// jy>=12 -> dual {reset, value}: value = sigmoid(reset*d)*(value*d)
// ---------------------------------------------------------------------------
__global__ __launch_bounds__(256) void k_parts(const float* __restrict__ inp,
                                               const short* __restrict__ Lp,
                                               const float* __restrict__ drops,
                                               float* __restrict__ query,
                                               float* __restrict__ keyv,
                                               float* __restrict__ value) {
  WAVE_SETUP
  const int jy = blockIdx.y;
  const float* Ap = &inp[(size_t)rowA * INP_D];
  auto loadA = [&](int kb) -> bf16x8 {
    const int k = kb * 32 + kg;
    return cvt8(*(const float4*)&Ap[k], *(const float4*)&Ap[k + 4]);
  };
  if (jy < 12) {
    float* dst = (jy < 6) ? query : keyv;
    const int nloc = ((jy < 6) ? jy : jy - 6) * 64;
    const int bn = jy * 4;
    f32x4 acc[4];
#pragma unroll
    for (int s = 0; s < 4; ++s) acc[s] = (f32x4){0.f, 0.f, 0.f, 0.f};
    mm_core<24, false>(loadA, Lp, bn, 96, nullptr, 0, 0, l, acc, nullptr);
#pragma unroll
    for (int i = 0; i < 4; ++i) {
      const int row = m0 + w * 16 + ((l >> 4) << 2) + i;
      const float d = drops[row];
#pragma unroll
      for (int s = 0; s < 4; ++s) {
        const int col = nloc + s * 16 + (l & 15);
        dst[(size_t)row * Q_D + col] = elu1f(acc[s][i] * d);
      }
    }
  } else {
    const int q = jy - 12;
    const int bn_r = 48 + q * 4, bn_v = 72 + q * 4;
    f32x4 a1[4], a2[4];
#pragma unroll
    for (int s = 0; s < 4; ++s) { a1[s] = (f32x4){0.f, 0.f, 0.f, 0.f}; a2[s] = (f32x4){0.f, 0.f, 0.f, 0.f}; }
    mm_core<24, true>(loadA, Lp, bn_r, 96, Lp, bn_v, 96, l, a1, a2);
#pragma unroll
    for (int i = 0; i < 4; ++i) {
      const int row = m0 + w * 16 + ((l >> 4) << 2) + i;
      const float d = drops[row];
#pragma unroll
      for (int s = 0; s < 4; ++s) {
        const int col = q * 64 + s * 16 + (l & 15);
        value[(size_t)row * E_D + col] = sigf(a1[s][i] * d) * (a2[s][i] * d);
      }
    }
  }
}

// ---------------------------------------------------------------------------
// proj GEMM: hpre = attn @ proj_W + inp
// ---------------------------------------------------------------------------
__global__ __launch_bounds__(256) void k_proj(const float* __restrict__ attn,
                                              const short* __restrict__ Bp,
                                              const float* __restrict__ inp,
                                              float* __restrict__ hpre) {
  WAVE_SETUP
  const int n0 = blockIdx.y * 64, bn = blockIdx.y * 4;
  const float* Ap = &attn[(size_t)rowA * E_D];
  auto loadA = [&](int kb) -> bf16x8 {
    const int k = kb * 32 + kg;
    return cvt8(*(const float4*)&Ap[k], *(const float4*)&Ap[k + 4]);
  };
  f32x4 acc[4];
#pragma unroll
  for (int s = 0; s < 4; ++s) acc[s] = (f32x4){0.f, 0.f, 0.f, 0.f};
  mm_core<12, false>(loadA, Bp, bn, 48, nullptr, 0, 0, l, acc, nullptr);
#pragma unroll
  for (int i = 0; i < 4; ++i) {
    const int row = m0 + w * 16 + ((l >> 4) << 2) + i;
#pragma unroll
    for (int s = 0; s < 4; ++s) {
      const int col = n0 + s * 16 + (l & 15);
      hpre[(size_t)row * INP_D + col] = acc[s][i] + inp[(size_t)row * INP_D + col];
    }
  }
}

// ---------------------------------------------------------------------------
// FFN dual GEMM: g = silu(h@W1) * (h@W2)
// ---------------------------------------------------------------------------
__global__ __launch_bounds__(256) void k_ffn(const float* __restrict__ h,
                                             const short* __restrict__ W1p,
                                             const short* __restrict__ W2p,
                                             float* __restrict__ g) {
  WAVE_SETUP
  const int n0 = blockIdx.y * 64, bn = blockIdx.y * 4;
  const float* Ap = &h[(size_t)rowA * INP_D];
  auto loadA = [&](int kb) -> bf16x8 {
    const int k = kb * 32 + kg;
    return cvt8(*(const float4*)&Ap[k], *(const float4*)&Ap[k + 4]);
  };
  f32x4 a1[4], a2[4];
#pragma unroll
  for (int s = 0; s < 4; ++s) { a1[s] = (f32x4){0.f, 0.f, 0.f, 0.f}; a2[s] = (f32x4){0.f, 0.f, 0.f, 0.f}; }
  mm_core<24, true>(loadA, W1p, bn, 96, W2p, bn, 96, l, a1, a2);
#pragma unroll
  for (int i = 0; i < 4; ++i) {
    const int row = m0 + w * 16 + ((l >> 4) << 2) + i;
#pragma unroll
    for (int s = 0; s < 4; ++s) {
      const int col = n0 + s * 16 + (l & 15);
      const float v1 = a1[s][i], v2 = a2[s][i];
      g[(size_t)row * DFF_D + col] = v1 * sigf(v1) * v2;
    }
  }
}

// ---------------------------------------------------------------------------
// out GEMM: out = g @ W3
// ---------------------------------------------------------------------------
__global__ __launch_bounds__(256) void k_out(const float* __restrict__ g,
                                             const short* __restrict__ Bp,
                                             float* __restrict__ out) {
  WAVE_SETUP
  const int n0 = blockIdx.y * 64, bn = blockIdx.y * 4;
  const float* Ap = &g[(size_t)rowA * DFF_D];
  auto loadA = [&](int kb) -> bf16x8 {
    const int k = kb * 32 + kg;
    return cvt8(*(const float4*)&Ap[k], *(const float4*)&Ap[k + 4]);
  };
  f32x4 acc[4];
#pragma unroll
  for (int s = 0; s < 4; ++s) acc[s] = (f32x4){0.f, 0.f, 0.f, 0.f};
  mm_core<48, false>(loadA, Bp, bn, 48, nullptr, 0, 0, l, acc, nullptr);
#pragma unroll
  for (int i = 0; i < 4; ++i) {
    const int row = m0 + w * 16 + ((l >> 4) << 2) + i;
#pragma unroll
    for (int s = 0; s < 4; ++s) {
      const int col = n0 + s * 16 + (l & 15);
      out[(size_t)row * INP_D + col] = acc[s][i];
    }
  }
}

// ---------------------------------------------------------------------------
// Segmented scan (proven R2 structure, direct buffer reads).
// Grid (6, 8, 4), 256 threads. q-chunk 48, 12 states/thread.
// ---------------------------------------------------------------------------
__global__ __launch_bounds__(256) void k_scan(const float* __restrict__ forget,
                                              const float* __restrict__ query,
                                              const float* __restrict__ keyv,
                                              const float* __restrict__ value,
                                              const float* __restrict__ is_first,
                                              const float* __restrict__ init_state,
                                              float* __restrict__ patt) {
  __shared__ float stg[144];
  __shared__ float pacc[256];
  const int tid = threadIdx.x;
  const int e  = blockIdx.x * 64 + (tid & 63);
  const int qg = tid >> 6;
  const int qc = blockIdx.y;
  const int b  = blockIdx.z;
  const int q0 = qc * 48 + qg * 12;

  float s[12], ini[12];
#pragma unroll
  for (int j = 0; j < 12; ++j) {
    ini[j] = init_state[((size_t)b * Q_D + q0 + j) * E_D + e];
    s[j]   = ini[j];
  }

  float stage_r = 0.0f, v_r, if_r;
  {
    const int tok = b;
    if (tid < 144) {
      const int which = tid / 48, o = tid % 48;
      const float* src = which == 0 ? forget : (which == 1 ? keyv : query);
      stage_r = src[(size_t)tok * Q_D + qc * 48 + o];
    }
    v_r  = value[(size_t)tok * E_D + e];
    if_r = 0.0f;
  }

  for (int t = 0; t < T_DIM; ++t) {
    const int tok = t * B_DIM + b;
    if (tid < 144) stg[tid] = stage_r;
    const float v  = v_r;
    const float ff = if_r;
    __syncthreads();
    if (t + 1 < T_DIM) {
      const int tok1 = tok + B_DIM;
      if (tid < 144) {
        const int which = tid / 48, o = tid % 48;
        const float* src = which == 0 ? forget : (which == 1 ? keyv : query);
        stage_r = src[(size_t)tok1 * Q_D + qc * 48 + o];
      }
      v_r  = value[(size_t)tok1 * E_D + e];
      if_r = is_first[tok1];
    }
    if (ff > 0.5f) {
#pragma unroll
      for (int j = 0; j < 12; ++j) s[j] = ini[j];
    }
    const float4* f4 = (const float4*)&stg[qg * 12];
    const float4* k4 = (const float4*)&stg[48 + qg * 12];
    const float4* q4 = (const float4*)&stg[96 + qg * 12];
    float p = 0.0f;
#pragma unroll
    for (int jj = 0; jj < 3; ++jj) {
      const float4 fv = f4[jj], kv = k4[jj], qv = q4[jj];
#pragma unroll
      for (int j2 = 0; j2 < 4; ++j2) {
        const int sj = jj * 4 + j2;
        s[sj] = fmaf((&fv.x)[j2], s[sj], (&kv.x)[j2] * v);
        p     = fmaf((&qv.x)[j2], s[sj], p);
      }
    }
    pacc[tid] = p;
    __syncthreads();
    if (tid < 64) {
      float r = pacc[tid] + pacc[tid + 64] + pacc[tid + 128] + pacc[tid + 192];
      patt[((size_t)qc * NTOK + tok) * E_D + blockIdx.x * 64 + tid] = r;
    }
    __syncthreads();
  }
}

// sum 8 scan slabs + RMS norm -> attn
__global__ __launch_bounds__(128) void ep_rms(const float* __restrict__ patt,
                                              const float* __restrict__ rms_w,
                                              float* __restrict__ attn) {
  const int tok = blockIdx.x, tid = threadIdx.x;
  float x[3], ss = 0.0f;
#pragma unroll
  for (int i = 0; i < 3; ++i) {
    const int e = i * 128 + tid;
    float a = 0.0f;
#pragma unroll
    for (int qc = 0; qc < 8; ++qc) a += patt[((size_t)qc * NTOK + tok) * E_D + e];
    x[i] = a;
    ss = fmaf(a, a, ss);
  }
#pragma unroll
  for (int off = 32; off; off >>= 1) ss += __shfl_down(ss, off, 64);
  __shared__ float r[2];
  const int wid = tid >> 6, lane = tid & 63;
  if (lane == 0) r[wid] = ss;
  __syncthreads();
  ss = r[0] + r[1];
  const float sc = rsqrtf(ss * (1.0f / E_D) + 1e-6f);
#pragma unroll
  for (int i = 0; i < 3; ++i) {
    const int e = i * 128 + tid;
    attn[(size_t)tok * E_D + e] = x[i] * sc * rms_w[e];
  }
}

// LayerNorm over hpre -> h
__global__ __launch_bounds__(256) void ep_ln(const float* __restrict__ hpre,
                                             const float* __restrict__ ln_w,
                                             const float* __restrict__ ln_b,
                                             float* __restrict__ h) {
  const int tok = blockIdx.x, tid = threadIdx.x;
  float x[3], s1 = 0.0f, s2 = 0.0f;
#pragma unroll
  for (int i = 0; i < 3; ++i) {
    x[i] = hpre[(size_t)tok * INP_D + i * 256 + tid];
    s1 += x[i];
    s2 = fmaf(x[i], x[i], s2);
  }
#pragma unroll
  for (int off = 32; off; off >>= 1) {
    s1 += __shfl_down(s1, off, 64);
    s2 += __shfl_down(s2, off, 64);
  }
  __shared__ float r1[4], r2[4];
  const int wid = tid >> 6, lane = tid & 63;
  if (lane == 0) { r1[wid] = s1; r2[wid] = s2; }
  __syncthreads();
  s1 = r1[0] + r1[1] + r1[2] + r1[3];
  s2 = r2[0] + r2[1] + r2[2] + r2[3];
  const float mean = s1 * (1.0f / INP_D);
  const float var  = s2 * (1.0f / INP_D) - mean * mean;
  const float sc   = rsqrtf(var + 1e-5f);
#pragma unroll
  for (int i = 0; i < 3; ++i) {
    const int c = i * 256 + tid;
    h[(size_t)tok * INP_D + c] = (x[i] - mean) * sc * ln_w[c] + ln_b[c];
  }
}

extern "C" void kernel_launch(void* const* d_in, const int* in_sizes, int n_in,
                              void* d_out, int out_size, void* d_ws, size_t ws_size,
                              hipStream_t stream) {
  (void)in_sizes; (void)n_in; (void)out_size; (void)ws_size;
  const float* inp        = (const float*)d_in[0];
  const float* is_first   = (const float*)d_in[1];
  const float* drops      = (const float*)d_in[2];
  const float* init_inp   = (const float*)d_in[3];
  const float* init_state = (const float*)d_in[4];
  const float* mix_mu     = (const float*)d_in[5];
  const float* mix_W      = (const float*)d_in[6];
  const float* layer_W    = (const float*)d_in[7];
  const float* proj_W     = (const float*)d_in[8];
  const float* rms_w      = (const float*)d_in[9];
  const float* ln_w       = (const float*)d_in[10];
  const float* ln_b       = (const float*)d_in[11];
  const float* W1         = (const float*)d_in[12];
  const float* W2         = (const float*)d_in[13];
  const float* W3         = (const float*)d_in[14];
  float* out = (float*)d_out;
  float* ws  = (float*)d_ws;
  short* wsb = (short*)(ws + WS_BF);

  float* forget = ws + WS_FORGET;
  float* query  = ws + WS_QUERY;
  float* keyv   = ws + WS_KEYV;
  float* value  = ws + WS_VALUE;
  float* patt   = ws + WS_PATT;
  float* attn   = ws + WS_ATTN;
  float* hpre   = ws + WS_HPRE;
  float* h      = ws + WS_H;
  float* g      = ws + WS_G;

  k_conv<<<2592, 256, 0, stream>>>(mix_W, layer_W, proj_W, W1, W2, W3, wsb);
  k_fg<<<dim3(4, 6), 256, 0, stream>>>(inp, is_first, init_inp, mix_mu,
                                       wsb + PK_MIX, drops, forget);
  k_parts<<<dim3(4, 18), 256, 0, stream>>>(inp, wsb + PK_LAYER, drops, query, keyv, value);
  k_scan<<<dim3(6, 8, 4), 256, 0, stream>>>(forget, query, keyv, value,
                                            is_first, init_state, patt);
  ep_rms<<<NTOK, 128, 0, stream>>>(patt, rms_w, attn);
  k_proj<<<dim3(4, 12), 256, 0, stream>>>(attn, wsb + PK_PROJ, inp, hpre);
  ep_ln<<<NTOK, 256, 0, stream>>>(hpre, ln_w, ln_b, h);
  k_ffn<<<dim3(4, 24), 256, 0, stream>>>(h, wsb + PK_W1, wsb + PK_W2, g);
  k_out<<<dim3(4, 12), 256, 0, stream>>>(g, wsb + PK_W3, out);
}

// Round 9
// 194.372 us; speedup vs baseline: 2.6255x; 1.0800x over previous
//
#include <hip/hip_runtime.h>
#include <hip/hip_bf16.h>

#define T_DIM 64
#define B_DIM 4
#define INP_D 768
#define Q_D   384
#define E_D   384
#define DFF_D 1536
#define NTOK  256

typedef short bf16x8 __attribute__((ext_vector_type(8)));
typedef float f32x4  __attribute__((ext_vector_type(4)));

__device__ __forceinline__ float sigf(float x)  { return 1.0f / (1.0f + __expf(-x)); }
__device__ __forceinline__ float elu1f(float x) { return x > 0.0f ? x + 1.0f : __expf(x); }

__device__ __forceinline__ short f2b(float x) {
  union { __hip_bfloat16 b; short s; } u;
  u.b = __float2bfloat16(x);
  return u.s;
}
__device__ __forceinline__ bf16x8 cvt8(float4 a, float4 b) {
  bf16x8 r;
  r[0] = f2b(a.x); r[1] = f2b(a.y); r[2] = f2b(a.z); r[3] = f2b(a.w);
  r[4] = f2b(b.x); r[5] = f2b(b.y); r[6] = f2b(b.z); r[7] = f2b(b.w);
  return r;
}

// ---------------------------------------------------------------------------
// Workspace layout (identical to R8). f32 region then packed-bf16 weights.
// ---------------------------------------------------------------------------
#define WS_FORGET 0
#define WS_QUERY  98304
#define WS_KEYV   196608
#define WS_VALUE  294912
#define WS_PATT   393216      // [8][256][384]
#define WS_ATTN   1179648
#define WS_HPRE   1277952
#define WS_H      1474560
#define WS_G      1671168     // [256][1536]
#define WS_BF     2064384     // bf16 region start (float offset; 16B aligned)
#define PK_MIX   0            // 768x384
#define PK_LAYER 294912       // 768x1536
#define PK_PROJ  1474560      // 384x768
#define PK_W1    1769472      // 768x1536
#define PK_W2    2949120      // 768x1536
#define PK_W3    4128768      // 1536x768  (end 5308416)

// ---------------------------------------------------------------------------
// Weight conversion (unchanged from R8, proven).
// ---------------------------------------------------------------------------
__global__ __launch_bounds__(256) void k_conv(const float* __restrict__ mixW,
                                              const float* __restrict__ layerW,
                                              const float* __restrict__ projW,
                                              const float* __restrict__ W1,
                                              const float* __restrict__ W2,
                                              const float* __restrict__ W3,
                                              short* __restrict__ wsb) {
  const int blk = blockIdx.x;
  const float* src; short* dst; int N, kb, nb64;
  if (blk < 144)        { src = mixW;   dst = wsb + PK_MIX;   N = 384;  int r = blk;        kb = r / 6;  nb64 = r % 6; }
  else if (blk < 720)   { src = layerW; dst = wsb + PK_LAYER; N = 1536; int r = blk - 144;  kb = r / 24; nb64 = r % 24; }
  else if (blk < 864)   { src = projW;  dst = wsb + PK_PROJ;  N = 768;  int r = blk - 720;  kb = r / 12; nb64 = r % 12; }
  else if (blk < 1440)  { src = W1;     dst = wsb + PK_W1;    N = 1536; int r = blk - 864;  kb = r / 24; nb64 = r % 24; }
  else if (blk < 2016)  { src = W2;     dst = wsb + PK_W2;    N = 1536; int r = blk - 1440; kb = r / 24; nb64 = r % 24; }
  else                  { src = W3;     dst = wsb + PK_W3;    N = 768;  int r = blk - 2016; kb = r / 12; nb64 = r % 12; }

  __shared__ float lds[32][68];
  const int tid = threadIdx.x;
  {
    const int r = tid >> 3, c8 = (tid & 7) * 8;
    const float* p = &src[(size_t)(kb * 32 + r) * N + nb64 * 64 + c8];
    *(float4*)&lds[r][c8]     = *(const float4*)p;
    *(float4*)&lds[r][c8 + 4] = *(const float4*)(p + 4);
  }
  __syncthreads();
  {
    const int nb = tid >> 6, lane = tid & 63, g = lane >> 4, c = lane & 15;
    unsigned int w[4];
#pragma unroll
    for (int jj = 0; jj < 4; ++jj) {
      unsigned short lo = (unsigned short)f2b(lds[g * 8 + jj * 2][nb * 16 + c]);
      unsigned short hi = (unsigned short)f2b(lds[g * 8 + jj * 2 + 1][nb * 16 + c]);
      w[jj] = (unsigned int)lo | ((unsigned int)hi << 16);
    }
    const int N16 = N >> 4;
    size_t o = ((size_t)kb * N16 + (nb64 * 4 + nb)) * 512 + lane * 8;
    uint4 pk; pk.x = w[0]; pk.y = w[1]; pk.z = w[2]; pk.w = w[3];
    *(uint4*)&dst[o] = pk;
  }
}

// ---------------------------------------------------------------------------
// MFMA core, SUBT 16-col subtiles per B (SUBT=2 -> 32-col wave tiles).
// ---------------------------------------------------------------------------
template<int KSTEPS, int SUBT, bool DUAL, class ALoad>
__device__ __forceinline__ void mm_core(ALoad loadA,
                                        const short* __restrict__ B1, int bn1, int N16a,
                                        const short* __restrict__ B2, int bn2, int N16b,
                                        int lane, f32x4* acc1, f32x4* acc2) {
  bf16x8 a_c = loadA(0);
  bf16x8 b1c[SUBT], b2c[SUBT];
#pragma unroll
  for (int s = 0; s < SUBT; ++s)
    b1c[s] = *(const bf16x8*)&B1[((size_t)(bn1 + s)) * 512 + lane * 8];
  if constexpr (DUAL) {
#pragma unroll
    for (int s = 0; s < SUBT; ++s)
      b2c[s] = *(const bf16x8*)&B2[((size_t)(bn2 + s)) * 512 + lane * 8];
  }
#pragma unroll 2
  for (int kb = 0; kb < KSTEPS; ++kb) {
    bf16x8 a_n = a_c;
    bf16x8 b1n[SUBT], b2n[SUBT];
    if (kb + 1 < KSTEPS) {
      a_n = loadA(kb + 1);
#pragma unroll
      for (int s = 0; s < SUBT; ++s)
        b1n[s] = *(const bf16x8*)&B1[((size_t)(kb + 1) * N16a + bn1 + s) * 512 + lane * 8];
      if constexpr (DUAL) {
#pragma unroll
        for (int s = 0; s < SUBT; ++s)
          b2n[s] = *(const bf16x8*)&B2[((size_t)(kb + 1) * N16b + bn2 + s) * 512 + lane * 8];
      }
    }
#pragma unroll
    for (int s = 0; s < SUBT; ++s)
      acc1[s] = __builtin_amdgcn_mfma_f32_16x16x32_bf16(a_c, b1c[s], acc1[s], 0, 0, 0);
    if constexpr (DUAL) {
#pragma unroll
      for (int s = 0; s < SUBT; ++s)
        acc2[s] = __builtin_amdgcn_mfma_f32_16x16x32_bf16(a_c, b2c[s], acc2[s], 0, 0, 0);
    }
    a_c = a_n;
#pragma unroll
    for (int s = 0; s < SUBT; ++s) b1c[s] = b1n[s];
    if constexpr (DUAL) {
#pragma unroll
      for (int s = 0; s < SUBT; ++s) b2c[s] = b2n[s];
    }
  }
}

#define WAVE_SETUP  const int tid = threadIdx.x, w = tid >> 6, l = tid & 63; \
                    const int m0 = blockIdx.x * 64; \
                    const int rowA = m0 + w * 16 + (l & 15); \
                    const int kg = (l >> 4) * 8; (void)kg;

// ---------------------------------------------------------------------------
// Merged fg + parts dispatch. Grid (4, 48), 32-col wave tiles.
//  y<12:  forget (mixed synth A, mix_W)          cols y*32      of Q_D
//  y<24:  query  = elu(parts*d)+1                cols (y-12)*32 of Q_D
//  y<36:  keyv   = elu(parts*d)+1                cols (y-24)*32
//  y>=36: dual reset/value -> value buffer       cols (y-36)*32 of E_D
// ---------------------------------------------------------------------------
__global__ __launch_bounds__(256) void k_qkvfg(const float* __restrict__ inp,
                                               const float* __restrict__ is_first,
                                               const float* __restrict__ init_inp,
                                               const float* __restrict__ mu,
                                               const short* __restrict__ Mixp,
                                               const short* __restrict__ Lp,
                                               const float* __restrict__ drops,
                                               float* __restrict__ forget,
                                               float* __restrict__ query,
                                               float* __restrict__ keyv,
                                               float* __restrict__ value) {
  WAVE_SETUP
  const int y = blockIdx.y;
  if (y < 12) {
    const int n0 = y * 32, bn = y * 2;
    const int tt = rowA >> 2, bb = rowA & 3;
    const float fr = (tt == 0) ? 1.0f : is_first[rowA];
    const float* lastp = (fr > 0.5f) ? &init_inp[bb * INP_D] : &inp[(size_t)(rowA - 4) * INP_D];
    const float* inpp  = &inp[(size_t)rowA * INP_D];
    auto loadA = [&](int kb) -> bf16x8 {
      const int k = kb * 32 + kg;
      float4 x0 = *(const float4*)&inpp[k],  x1 = *(const float4*)&inpp[k + 4];
      float4 l0 = *(const float4*)&lastp[k], l1 = *(const float4*)&lastp[k + 4];
      float4 m0v = *(const float4*)&mu[k],   m1v = *(const float4*)&mu[k + 4];
      float4 r0, r1;
      r0.x = m0v.x * x0.x + (1.0f - m0v.x) * l0.x;
      r0.y = m0v.y * x0.y + (1.0f - m0v.y) * l0.y;
      r0.z = m0v.z * x0.z + (1.0f - m0v.z) * l0.z;
      r0.w = m0v.w * x0.w + (1.0f - m0v.w) * l0.w;
      r1.x = m1v.x * x1.x + (1.0f - m1v.x) * l1.x;
      r1.y = m1v.y * x1.y + (1.0f - m1v.y) * l1.y;
      r1.z = m1v.z * x1.z + (1.0f - m1v.z) * l1.z;
      r1.w = m1v.w * x1.w + (1.0f - m1v.w) * l1.w;
      return cvt8(r0, r1);
    };
    f32x4 acc[2] = {(f32x4){0.f,0.f,0.f,0.f}, (f32x4){0.f,0.f,0.f,0.f}};
    mm_core<24, 2, false>(loadA, Mixp, bn, 24, nullptr, 0, 0, l, acc, nullptr);
#pragma unroll
    for (int i = 0; i < 4; ++i) {
      const int row = m0 + w * 16 + ((l >> 4) << 2) + i;
      const float d = drops[row];
#pragma unroll
      for (int s = 0; s < 2; ++s) {
        const int col = n0 + s * 16 + (l & 15);
        forget[(size_t)row * Q_D + col] = (sigf(acc[s][i]) - 1.0f) * d + 1.0f;
      }
    }
    return;
  }
  const float* Ap = &inp[(size_t)rowA * INP_D];
  auto loadA = [&](int kb) -> bf16x8 {
    const int k = kb * 32 + kg;
    return cvt8(*(const float4*)&Ap[k], *(const float4*)&Ap[k + 4]);
  };
  if (y < 36) {
    const bool isq = (y < 24);
    const int yy = isq ? y - 12 : y - 24;
    float* dst = isq ? query : keyv;
    const int bn = (isq ? 0 : 24) + yy * 2;
    f32x4 acc[2] = {(f32x4){0.f,0.f,0.f,0.f}, (f32x4){0.f,0.f,0.f,0.f}};
    mm_core<24, 2, false>(loadA, Lp, bn, 96, nullptr, 0, 0, l, acc, nullptr);
#pragma unroll
    for (int i = 0; i < 4; ++i) {
      const int row = m0 + w * 16 + ((l >> 4) << 2) + i;
      const float d = drops[row];
#pragma unroll
      for (int s = 0; s < 2; ++s) {
        const int col = yy * 32 + s * 16 + (l & 15);
        dst[(size_t)row * Q_D + col] = elu1f(acc[s][i] * d);
      }
    }
  } else {
    const int q = y - 36;
    const int bn_r = 48 + q * 2, bn_v = 72 + q * 2;
    f32x4 a1[2] = {(f32x4){0.f,0.f,0.f,0.f}, (f32x4){0.f,0.f,0.f,0.f}};
    f32x4 a2[2] = {(f32x4){0.f,0.f,0.f,0.f}, (f32x4){0.f,0.f,0.f,0.f}};
    mm_core<24, 2, true>(loadA, Lp, bn_r, 96, Lp, bn_v, 96, l, a1, a2);
#pragma unroll
    for (int i = 0; i < 4; ++i) {
      const int row = m0 + w * 16 + ((l >> 4) << 2) + i;
      const float d = drops[row];
#pragma unroll
      for (int s = 0; s < 2; ++s) {
        const int col = q * 32 + s * 16 + (l & 15);
        value[(size_t)row * E_D + col] = sigf(a1[s][i] * d) * (a2[s][i] * d);
      }
    }
  }
}

// ---------------------------------------------------------------------------
// proj GEMM: hpre = attn @ proj_W + inp. Grid (4, 24), 32-col tiles.
// ---------------------------------------------------------------------------
__global__ __launch_bounds__(256) void k_proj(const float* __restrict__ attn,
                                              const short* __restrict__ Bp,
                                              const float* __restrict__ inp,
                                              float* __restrict__ hpre) {
  WAVE_SETUP
  const int n0 = blockIdx.y * 32, bn = blockIdx.y * 2;
  const float* Ap = &attn[(size_t)rowA * E_D];
  auto loadA = [&](int kb) -> bf16x8 {
    const int k = kb * 32 + kg;
    return cvt8(*(const float4*)&Ap[k], *(const float4*)&Ap[k + 4]);
  };
  f32x4 acc[2] = {(f32x4){0.f,0.f,0.f,0.f}, (f32x4){0.f,0.f,0.f,0.f}};
  mm_core<12, 2, false>(loadA, Bp, bn, 48, nullptr, 0, 0, l, acc, nullptr);
#pragma unroll
  for (int i = 0; i < 4; ++i) {
    const int row = m0 + w * 16 + ((l >> 4) << 2) + i;
#pragma unroll
    for (int s = 0; s < 2; ++s) {
      const int col = n0 + s * 16 + (l & 15);
      hpre[(size_t)row * INP_D + col] = acc[s][i] + inp[(size_t)row * INP_D + col];
    }
  }
}

// ---------------------------------------------------------------------------
// FFN dual GEMM: g = silu(h@W1) * (h@W2). Grid (4, 48), 32-col tiles.
// ---------------------------------------------------------------------------
__global__ __launch_bounds__(256) void k_ffn(const float* __restrict__ h,
                                             const short* __restrict__ W1p,
                                             const short* __restrict__ W2p,
                                             float* __restrict__ g) {
  WAVE_SETUP
  const int n0 = blockIdx.y * 32, bn = blockIdx.y * 2;
  const float* Ap = &h[(size_t)rowA * INP_D];
  auto loadA = [&](int kb) -> bf16x8 {
    const int k = kb * 32 + kg;
    return cvt8(*(const float4*)&Ap[k], *(const float4*)&Ap[k + 4]);
  };
  f32x4 a1[2] = {(f32x4){0.f,0.f,0.f,0.f}, (f32x4){0.f,0.f,0.f,0.f}};
  f32x4 a2[2] = {(f32x4){0.f,0.f,0.f,0.f}, (f32x4){0.f,0.f,0.f,0.f}};
  mm_core<24, 2, true>(loadA, W1p, bn, 96, W2p, bn, 96, l, a1, a2);
#pragma unroll
  for (int i = 0; i < 4; ++i) {
    const int row = m0 + w * 16 + ((l >> 4) << 2) + i;
#pragma unroll
    for (int s = 0; s < 2; ++s) {
      const int col = n0 + s * 16 + (l & 15);
      const float v1 = a1[s][i], v2 = a2[s][i];
      g[(size_t)row * DFF_D + col] = v1 * sigf(v1) * v2;
    }
  }
}

// ---------------------------------------------------------------------------
// out GEMM: out = g @ W3. Grid (4, 24), 32-col tiles.
// ---------------------------------------------------------------------------
__global__ __launch_bounds__(256) void k_out(const float* __restrict__ g,
                                             const short* __restrict__ Bp,
                                             float* __restrict__ out) {
  WAVE_SETUP
  const int n0 = blockIdx.y * 32, bn = blockIdx.y * 2;
  const float* Ap = &g[(size_t)rowA * DFF_D];
  auto loadA = [&](int kb) -> bf16x8 {
    const int k = kb * 32 + kg;
    return cvt8(*(const float4*)&Ap[k], *(const float4*)&Ap[k + 4]);
  };
  f32x4 acc[2] = {(f32x4){0.f,0.f,0.f,0.f}, (f32x4){0.f,0.f,0.f,0.f}};
  mm_core<48, 2, false>(loadA, Bp, bn, 48, nullptr, 0, 0, l, acc, nullptr);
#pragma unroll
  for (int i = 0; i < 4; ++i) {
    const int row = m0 + w * 16 + ((l >> 4) << 2) + i;
#pragma unroll
    for (int s = 0; s < 2; ++s) {
      const int col = n0 + s * 16 + (l & 15);
      out[(size_t)row * INP_D + col] = acc[s][i];
    }
  }
}

// ---------------------------------------------------------------------------
// Segmented scan (unchanged from R8, proven).
// ---------------------------------------------------------------------------
__global__ __launch_bounds__(256) void k_scan(const float* __restrict__ forget,
                                              const float* __restrict__ query,
                                              const float* __restrict__ keyv,
                                              const float* __restrict__ value,
                                              const float* __restrict__ is_first,
                                              const float* __restrict__ init_state,
                                              float* __restrict__ patt) {
  __shared__ float stg[144];
  __shared__ float pacc[256];
  const int tid = threadIdx.x;
  const int e  = blockIdx.x * 64 + (tid & 63);
  const int qg = tid >> 6;
  const int qc = blockIdx.y;
  const int b  = blockIdx.z;
  const int q0 = qc * 48 + qg * 12;

  float s[12], ini[12];
#pragma unroll
  for (int j = 0; j < 12; ++j) {
    ini[j] = init_state[((size_t)b * Q_D + q0 + j) * E_D + e];
    s[j]   = ini[j];
  }

  float stage_r = 0.0f, v_r, if_r;
  {
    const int tok = b;
    if (tid < 144) {
      const int which = tid / 48, o = tid % 48;
      const float* src = which == 0 ? forget : (which == 1 ? keyv : query);
      stage_r = src[(size_t)tok * Q_D + qc * 48 + o];
    }
    v_r  = value[(size_t)tok * E_D + e];
    if_r = 0.0f;
  }

  for (int t = 0; t < T_DIM; ++t) {
    const int tok = t * B_DIM + b;
    if (tid < 144) stg[tid] = stage_r;
    const float v  = v_r;
    const float ff = if_r;
    __syncthreads();
    if (t + 1 < T_DIM) {
      const int tok1 = tok + B_DIM;
      if (tid < 144) {
        const int which = tid / 48, o = tid % 48;
        const float* src = which == 0 ? forget : (which == 1 ? keyv : query);
        stage_r = src[(size_t)tok1 * Q_D + qc * 48 + o];
      }
      v_r  = value[(size_t)tok1 * E_D + e];
      if_r = is_first[tok1];
    }
    if (ff > 0.5f) {
#pragma unroll
      for (int j = 0; j < 12; ++j) s[j] = ini[j];
    }
    const float4* f4 = (const float4*)&stg[qg * 12];
    const float4* k4 = (const float4*)&stg[48 + qg * 12];
    const float4* q4 = (const float4*)&stg[96 + qg * 12];
    float p = 0.0f;
#pragma unroll
    for (int jj = 0; jj < 3; ++jj) {
      const float4 fv = f4[jj], kv = k4[jj], qv = q4[jj];
#pragma unroll
      for (int j2 = 0; j2 < 4; ++j2) {
        const int sj = jj * 4 + j2;
        s[sj] = fmaf((&fv.x)[j2], s[sj], (&kv.x)[j2] * v);
        p     = fmaf((&qv.x)[j2], s[sj], p);
      }
    }
    pacc[tid] = p;
    __syncthreads();
    if (tid < 64) {
      float r = pacc[tid] + pacc[tid + 64] + pacc[tid + 128] + pacc[tid + 192];
      patt[((size_t)qc * NTOK + tok) * E_D + blockIdx.x * 64 + tid] = r;
    }
    __syncthreads();
  }
}

// sum 8 scan slabs + RMS norm -> attn (unchanged)
__global__ __launch_bounds__(128) void ep_rms(const float* __restrict__ patt,
                                              const float* __restrict__ rms_w,
                                              float* __restrict__ attn) {
  const int tok = blockIdx.x, tid = threadIdx.x;
  float x[3], ss = 0.0f;
#pragma unroll
  for (int i = 0; i < 3; ++i) {
    const int e = i * 128 + tid;
    float a = 0.0f;
#pragma unroll
    for (int qc = 0; qc < 8; ++qc) a += patt[((size_t)qc * NTOK + tok) * E_D + e];
    x[i] = a;
    ss = fmaf(a, a, ss);
  }
#pragma unroll
  for (int off = 32; off; off >>= 1) ss += __shfl_down(ss, off, 64);
  __shared__ float r[2];
  const int wid = tid >> 6, lane = tid & 63;
  if (lane == 0) r[wid] = ss;
  __syncthreads();
  ss = r[0] + r[1];
  const float sc = rsqrtf(ss * (1.0f / E_D) + 1e-6f);
#pragma unroll
  for (int i = 0; i < 3; ++i) {
    const int e = i * 128 + tid;
    attn[(size_t)tok * E_D + e] = x[i] * sc * rms_w[e];
  }
}

// LayerNorm over hpre -> h (unchanged)
__global__ __launch_bounds__(256) void ep_ln(const float* __restrict__ hpre,
                                             const float* __restrict__ ln_w,
                                             const float* __restrict__ ln_b,
                                             float* __restrict__ h) {
  const int tok = blockIdx.x, tid = threadIdx.x;
  float x[3], s1 = 0.0f, s2 = 0.0f;
#pragma unroll
  for (int i = 0; i < 3; ++i) {
    x[i] = hpre[(size_t)tok * INP_D + i * 256 + tid];
    s1 += x[i];
    s2 = fmaf(x[i], x[i], s2);
  }
#pragma unroll
  for (int off = 32; off; off >>= 1) {
    s1 += __shfl_down(s1, off, 64);
    s2 += __shfl_down(s2, off, 64);
  }
  __shared__ float r1[4], r2[4];
  const int wid = tid >> 6, lane = tid & 63;
  if (lane == 0) { r1[wid] = s1; r2[wid] = s2; }
  __syncthreads();
  s1 = r1[0] + r1[1] + r1[2] + r1[3];
  s2 = r2[0] + r2[1] + r2[2] + r2[3];
  const float mean = s1 * (1.0f / INP_D);
  const float var  = s2 * (1.0f / INP_D) - mean * mean;
  const float sc   = rsqrtf(var + 1e-5f);
#pragma unroll
  for (int i = 0; i < 3; ++i) {
    const int c = i * 256 + tid;
    h[(size_t)tok * INP_D + c] = (x[i] - mean) * sc * ln_w[c] + ln_b[c];
  }
}

extern "C" void kernel_launch(void* const* d_in, const int* in_sizes, int n_in,
                              void* d_out, int out_size, void* d_ws, size_t ws_size,
                              hipStream_t stream) {
  (void)in_sizes; (void)n_in; (void)out_size; (void)ws_size;
  const float* inp        = (const float*)d_in[0];
  const float* is_first   = (const float*)d_in[1];
  const float* drops      = (const float*)d_in[2];
  const float* init_inp   = (const float*)d_in[3];
  const float* init_state = (const float*)d_in[4];
  const float* mix_mu     = (const float*)d_in[5];
  const float* mix_W      = (const float*)d_in[6];
  const float* layer_W    = (const float*)d_in[7];
  const float* proj_W     = (const float*)d_in[8];
  const float* rms_w      = (const float*)d_in[9];
  const float* ln_w       = (const float*)d_in[10];
  const float* ln_b       = (const float*)d_in[11];
  const float* W1         = (const float*)d_in[12];
  const float* W2         = (const float*)d_in[13];
  const float* W3         = (const float*)d_in[14];
  float* out = (float*)d_out;
  float* ws  = (float*)d_ws;
  short* wsb = (short*)(ws + WS_BF);

  float* forget = ws + WS_FORGET;
  float* query  = ws + WS_QUERY;
  float* keyv   = ws + WS_KEYV;
  float* value  = ws + WS_VALUE;
  float* patt   = ws + WS_PATT;
  float* attn   = ws + WS_ATTN;
  float* hpre   = ws + WS_HPRE;
  float* h      = ws + WS_H;
  float* g      = ws + WS_G;

  k_conv<<<2592, 256, 0, stream>>>(mix_W, layer_W, proj_W, W1, W2, W3, wsb);
  k_qkvfg<<<dim3(4, 48), 256, 0, stream>>>(inp, is_first, init_inp, mix_mu,
                                           wsb + PK_MIX, wsb + PK_LAYER, drops,
                                           forget, query, keyv, value);
  k_scan<<<dim3(6, 8, 4), 256, 0, stream>>>(forget, query, keyv, value,
                                            is_first, init_state, patt);
  ep_rms<<<NTOK, 128, 0, stream>>>(patt, rms_w, attn);
  k_proj<<<dim3(4, 24), 256, 0, stream>>>(attn, wsb + PK_PROJ, inp, hpre);
  ep_ln<<<NTOK, 256, 0, stream>>>(hpre, ln_w, ln_b, h);
  k_ffn<<<dim3(4, 48), 256, 0, stream>>>(h, wsb + PK_W1, wsb + PK_W2, g);
  k_out<<<dim3(4, 24), 256, 0, stream>>>(g, wsb + PK_W3, out);
}